// Round 11
// baseline (103.318 us; speedup 1.0000x reference)
//
#include <hip/hip_runtime.h>
#include <math.h>

// PHOSA interaction loss, MI355X — round 11: raise stream MLP + stream share.
// Diagnosis across r6-r10: phase1 pinned at ~60 us with HBM 20% / VALU 12% /
// occ 75% — HBM under-driven. Per-CU HBM share needs ~36 outstanding
// 256 B wave-loads; stream blocks were 56% of the grid with ~3 loads in
// flight per wave (marginal). Fixes, both bitwise-neutral:
//  (1) stream loops unrolled x4 -> 12 independent loads in flight per wave
//      (same accumulator order -> bitwise identical sums).
//  (2) each gather block now does TWO parts (g, g+4) sequentially with the
//      identical per-part body -> gather blocks halved, units/batch 36->28,
//      stream share 56%->71%.
constexpr int B_   = 256;
constexpr int NS_  = 10475;
constexpr int NO_  = 65536;
constexpr int P_   = 8;
constexpr int KS_  = 1024;
constexpr int KO_  = 2048;
constexpr int NBLK_S = 4;    // stream blocks per batch, smpl
constexpr int NBLK_O = 16;   // stream blocks per batch, object
constexpr float EPS_ = 1e-9f;
constexpr float ZTH_ = 5.0f;

// per-batch units: 16 objsum + 4 objgather(2 parts) + 4 smplsum + 4 smplgather(2 parts)
constexpr int GO_ = 4;                                   // obj gather blocks/batch
constexpr int GS_ = 4;                                   // smpl gather blocks/batch
constexpr int UNITS_PER_B = NBLK_O + GO_ + NBLK_S + GS_; // 28
constexpr int NXCD = 8;
constexpr int NSLOT = B_ / NXCD;                         // 32

// 16 B vector with 4 B alignment (emits global_load_dwordx4 from 12 B stride).
typedef float f32x4a4 __attribute__((ext_vector_type(4), aligned(4)));

#define DEV_INLINE __device__ __forceinline__

DEV_INLINE float wredsum(float v) {
#pragma unroll
    for (int o = 32; o; o >>= 1) v += __shfl_down(v, o);
    return v;
}
DEV_INLINE float wredmin(float v) {
#pragma unroll
    for (int o = 32; o; o >>= 1) v = fminf(v, __shfl_down(v, o));
    return v;
}
DEV_INLINE float wredmax(float v) {
#pragma unroll
    for (int o = 32; o; o >>= 1) v = fmaxf(v, __shfl_down(v, o));
    return v;
}

// ---------------------------------------------------------------------------
// Stream role: per-batch component partial sums. Same accumulation order as
// rounds 1-10 (unrolling preserves the += sequence) -> bitwise identical.
// ---------------------------------------------------------------------------
template <int N, int NBLK>
DEV_INLINE void batch_sum_body(const float* __restrict__ v, int b, int blk,
                               float* __restrict__ out) {
    const int chunk = (N + NBLK - 1) / NBLK;
    const int s = blk * chunk;
    const int e = min(N, s + chunk);
    const float* base = v + (size_t)b * N * 3;
    float sx = 0.f, sy = 0.f, sz = 0.f;
#pragma unroll 4
    for (int i = s + (int)threadIdx.x; i < e; i += 256) {
        const float* p = base + (size_t)i * 3;
        sx += p[0];
        sy += p[1];
        sz += p[2];
    }
    __shared__ float red[3][4];
    float r0 = wredsum(sx), r1 = wredsum(sy), r2 = wredsum(sz);
    const int lane = threadIdx.x & 63, wv = threadIdx.x >> 6;
    if (lane == 0) { red[0][wv] = r0; red[1][wv] = r1; red[2][wv] = r2; }
    __syncthreads();
    if (threadIdx.x == 0) {
        float* o = out + ((size_t)b * NBLK + blk) * 3;
        o[0] = red[0][0] + red[0][1] + red[0][2] + red[0][3];
        o[1] = red[1][0] + red[1][1] + red[1][2] + red[1][3];
        o[2] = red[2][0] + red[2][1] + red[2][2] + red[2][3];
    }
}

// ---------------------------------------------------------------------------
// Gather role: TWO parts (p0, p0+4) sequentially; each part's body is the
// verbatim round-8/10 single-part body (same 256-thread layout, same order)
// -> per-part stats bitwise identical.
// ---------------------------------------------------------------------------
template <int N, int K>
DEV_INLINE void part_stats_body2(const float* __restrict__ v,
                                 const int* __restrict__ pidx,
                                 const float* __restrict__ Ks, int b, int p0,
                                 float* __restrict__ out) {
    const float fx = Ks[b * 9 + 0];
    const float cx = Ks[b * 9 + 2];
    const float fy = Ks[b * 9 + 4];
    const float cy = Ks[b * 9 + 5];
    const float* base = v + (size_t)b * N * 3;
    const bool lastBatch = (b == B_ - 1);
    const int lane = threadIdx.x & 63, wv = threadIdx.x >> 6;
    __shared__ float red[4][9];

    constexpr int ITER = K / 256;
#pragma unroll 1
    for (int pi = 0; pi < 2; ++pi) {
        const int p = p0 + pi * 4;
        const int* idx = pidx + (size_t)p * K;

        int ids[ITER];
#pragma unroll
        for (int j = 0; j < ITER; ++j) ids[j] = idx[threadIdx.x + j * 256];

        float vx[ITER], vy[ITER], vz[ITER];
#pragma unroll
        for (int j = 0; j < ITER; ++j) {
            const bool shift = lastBatch && (ids[j] == N - 1);
            const float* vp = base + (size_t)ids[j] * 3 - (shift ? 1 : 0);
            const f32x4a4 f = *reinterpret_cast<const f32x4a4*>(vp);
            vx[j] = shift ? f.y : f.x;
            vy[j] = shift ? f.z : f.y;
            vz[j] = shift ? f.w : f.z;
        }

        float umin = INFINITY, umax = -INFINITY;
        float wmin = INFINITY, wmax = -INFINITY;
        float zmin = INFINITY, zmax = -INFINITY;
        float sx = 0.f, sy = 0.f, sz = 0.f;
#pragma unroll
        for (int j = 0; j < ITER; ++j) {
            const float x = vx[j], y = vy[j], z = vz[j];
            sx += x; sy += y; sz += z;
            zmin = fminf(zmin, z); zmax = fmaxf(zmax, z);
            float u, w;
            {
#pragma clang fp contract(off)
                const float zd = z + EPS_;
                const float x_ = x / zd;
                const float y_ = (-y) / zd;
                u = fx * x_ + cx;
                w = 1.0f - (fy * y_ + cy);
                u = 2.0f * (u - 0.5f);
                w = 2.0f * (w - 0.5f);
            }
            umin = fminf(umin, u); umax = fmaxf(umax, u);
            wmin = fminf(wmin, w); wmax = fmaxf(wmax, w);
        }

        float r[9];
        r[0] = wredmin(umin); r[1] = wredmax(umax);
        r[2] = wredmin(wmin); r[3] = wredmax(wmax);
        r[4] = wredmin(zmin); r[5] = wredmax(zmax);
        r[6] = wredsum(sx);   r[7] = wredsum(sy); r[8] = wredsum(sz);
        __syncthreads();   // red[] may still be read by thread 0 of prev part
        if (lane == 0) {
#pragma unroll
            for (int q = 0; q < 9; ++q) red[wv][q] = r[q];
        }
        __syncthreads();
        if (threadIdx.x == 0) {
            float* o = out + ((size_t)b * P_ + p) * 9;
            o[0] = fminf(fminf(red[0][0], red[1][0]), fminf(red[2][0], red[3][0]));
            o[1] = fmaxf(fmaxf(red[0][1], red[1][1]), fmaxf(red[2][1], red[3][1]));
            o[2] = fminf(fminf(red[0][2], red[1][2]), fminf(red[2][2], red[3][2]));
            o[3] = fmaxf(fmaxf(red[0][3], red[1][3]), fmaxf(red[2][3], red[3][3]));
            o[4] = fminf(fminf(red[0][4], red[1][4]), fminf(red[2][4], red[3][4]));
            o[5] = fmaxf(fmaxf(red[0][5], red[1][5]), fmaxf(red[2][5], red[3][5]));
            o[6] = red[0][6] + red[1][6] + red[2][6] + red[3][6];
            o[7] = red[0][7] + red[1][7] + red[2][7] + red[3][7];
            o[8] = red[0][8] + red[1][8] + red[2][8] + red[3][8];
        }
    }
}

// ---------------------------------------------------------------------------
// Phase 1: gid -> xcd = gid&7, unit = gid>>3, slot = unit/28, role = unit%28.
// Stream roles: batch slot*8+xcd. Gather roles: previous slot's batch.
// role: [0,16) objsum | [16,20) objgather(2p) | [20,24) smplsum | [24,28) smplgather(2p)
// ---------------------------------------------------------------------------
__global__ __launch_bounds__(256) void phase1_kernel(
        const float* __restrict__ obj, const float* __restrict__ smpl,
        const float* __restrict__ Ks,
        const int* __restrict__ sidx, const int* __restrict__ oidx,
        float* __restrict__ sumO, float* __restrict__ sumS,
        float* __restrict__ statsO, float* __restrict__ statsS) {
    const int gid = blockIdx.x;
    const int xcd = gid & (NXCD - 1);
    const int unit = gid >> 3;
    const int slot = unit / UNITS_PER_B;
    const int role = unit % UNITS_PER_B;
    const int bs = slot * NXCD + xcd;                               // stream batch
    const int bg = ((slot + NSLOT - 1) & (NSLOT - 1)) * NXCD + xcd; // gather batch
    if (role < NBLK_O) {
        batch_sum_body<NO_, NBLK_O>(obj, bs, role, sumO);
    } else if (role < NBLK_O + GO_) {
        part_stats_body2<NO_, KO_>(obj, oidx, Ks, bg, role - NBLK_O, statsO);
    } else if (role < NBLK_O + GO_ + NBLK_S) {
        batch_sum_body<NS_, NBLK_S>(smpl, bs, role - (NBLK_O + GO_), sumS);
    } else {
        part_stats_body2<NS_, KS_>(smpl, sidx, Ks, bg,
                                   role - (NBLK_O + GO_ + NBLK_S), statsS);
    }
}

// ---------------------------------------------------------------------------
// Kernel D: per-batch pair masking + partial sums (verbatim round-2/6/8).
// ---------------------------------------------------------------------------
__global__ __launch_bounds__(64) void pair_kernel(
        const float* __restrict__ statsS, const float* __restrict__ statsO,
        float* __restrict__ partial) {
#pragma clang fp contract(off)
    const int b = blockIdx.x;
    __shared__ float sS[P_][9];
    __shared__ float sO[P_][9];
    const int t = threadIdx.x;
    for (int i = t; i < 2 * P_ * 9; i += 64) {
        if (i < P_ * 9) sS[i / 9][i % 9] = statsS[(size_t)b * P_ * 9 + i];
        else {
            const int u = i - P_ * 9;
            sO[u / 9][u % 9] = statsO[(size_t)b * P_ * 9 + u];
        }
    }
    __syncthreads();

    const int ps = t >> 3;
    const int po = t & 7;

    const float* ssp = sS[po];
    const float* sop = sO[po];
    const float pcu = (ssp[0] + ssp[1]) * 0.5f;
    const float phu = (ssp[1] - ssp[0]) * 0.5f * 1.5f;
    const float pcw = (ssp[2] + ssp[3]) * 0.5f;
    const float phw = (ssp[3] - ssp[2]) * 0.5f * 1.5f;
    const float px0 = pcu - phu, px1 = pcu + phu;
    const float py0 = pcw - phw, py1 = pcw + phw;
    const float ocu = (sop[0] + sop[1]) * 0.5f;
    const float ohu = (sop[1] - sop[0]) * 0.5f * 1.5f;
    const float ocw = (sop[2] + sop[3]) * 0.5f;
    const float ohw = (sop[3] - sop[2]) * 0.5f * 1.5f;
    const float ox0 = ocu - ohu, ox1 = ocu + ohu;
    const float oy0 = ocw - ohw, oy1 = ocw + ohw;
    const bool ov = !((ox0 > px1) || (px0 > ox1) || (oy0 > py1) || (py0 > oy1));

    const float a  = sS[ps][4];
    const float bm = sS[ps][5];
    const float c  = sO[po][4];
    const float d  = sO[po][5];
    const float gap = fminf(fabsf(c - bm), fabsf(a - d));
    const float zd = ((d >= a) && (bm >= c)) ? 0.f : gap;
    const bool m = ov && (zd < ZTH_);

    const float ms0 = sS[ps][6] / (float)KS_;
    const float ms1 = sS[ps][7] / (float)KS_;
    const float ms2 = sS[ps][8] / (float)KS_;
    const float mo0 = sO[po][6] / (float)KO_;
    const float mo1 = sO[po][7] / (float)KO_;
    const float mo2 = sO[po][8] / (float)KO_;
    const float d0 = ms0 - mo0, d1 = ms1 - mo1, d2 = ms2 - mo2;
    const float pm = (d0 * d0 + d1 * d1 + d2 * d2) / 3.0f;

    float psum = m ? pm : 0.f;
    float pcnt = m ? 1.f : 0.f;
    psum = wredsum(psum);
    pcnt = wredsum(pcnt);
    if (t == 0) {
        partial[(size_t)b * 2 + 0] = psum;
        partial[(size_t)b * 2 + 1] = pcnt;
    }
}

// ---------------------------------------------------------------------------
// Kernel E: loss_inter + final reduce (verbatim round-6/8).
// ---------------------------------------------------------------------------
__global__ __launch_bounds__(256) void last_kernel(
        const float* __restrict__ sumS, const float* __restrict__ sumO,
        const float* __restrict__ pairPartial, float* __restrict__ out) {
    const int t = threadIdx.x;
    float d2 = 0.f;
#pragma unroll
    for (int c = 0; c < 3; ++c) {
        float ss = 0.f, so = 0.f;
#pragma unroll
        for (int k = 0; k < NBLK_S; ++k) ss += sumS[((size_t)t * NBLK_S + k) * 3 + c];
#pragma unroll
        for (int k = 0; k < NBLK_O; ++k) so += sumO[((size_t)t * NBLK_O + k) * 3 + c];
        const float ms = ss / (float)NS_;
        const float mo = so / (float)NO_;
        const float d = ms - mo;
        d2 += d * d;
    }
    float s = pairPartial[(size_t)t * 2 + 0];
    float c2 = pairPartial[(size_t)t * 2 + 1];
    __shared__ float rli[4], rs[4], rc[4];
    const float rl = wredsum(d2);
    const float ss2 = wredsum(s);
    const float cc = wredsum(c2);
    const int lane = t & 63, wv = t >> 6;
    if (lane == 0) { rli[wv] = rl; rs[wv] = ss2; rc[wv] = cc; }
    __syncthreads();
    if (t == 0) {
        const float tot = rli[0] + rli[1] + rli[2] + rli[3];
        out[0] = tot / (3.0f * (float)B_) / (float)B_;
        const float S = rs[0] + rs[1] + rs[2] + rs[3];
        const float C = rc[0] + rc[1] + rc[2] + rc[3];
        out[1] = (C > 0.f) ? (S / C) : 0.f;
    }
}

// ---------------------------------------------------------------------------
extern "C" void kernel_launch(void* const* d_in, const int* in_sizes, int n_in,
                              void* d_out, int out_size, void* d_ws, size_t ws_size,
                              hipStream_t stream) {
    const float* smpl = (const float*)d_in[0];
    const float* obj  = (const float*)d_in[1];
    const float* Ks   = (const float*)d_in[2];
    const int*   sidx = (const int*)d_in[3];
    const int*   oidx = (const int*)d_in[4];
    float* out = (float*)d_out;

    float* w = (float*)d_ws;
    float* sumO   = w;                                 // 256*16*3 = 12288
    float* sumS   = sumO + (size_t)B_ * NBLK_O * 3;    // 256*4*3  = 3072
    float* statsS = sumS + (size_t)B_ * NBLK_S * 3;    // 256*8*9  = 18432
    float* statsO = statsS + (size_t)B_ * P_ * 9;      // 256*8*9  = 18432
    float* pairP  = statsO + (size_t)B_ * P_ * 9;      // 512

    phase1_kernel<<<B_ * UNITS_PER_B, 256, 0, stream>>>(
        obj, smpl, Ks, sidx, oidx, sumO, sumS, statsO, statsS);
    pair_kernel<<<B_, 64, 0, stream>>>(statsS, statsO, pairP);
    last_kernel<<<1, 256, 0, stream>>>(sumS, sumO, pairP, out);
}

// Round 12
// 63.900 us; speedup vs baseline: 1.6169x; 1.6169x over previous
//
#include <hip/hip_runtime.h>
#include <math.h>

// PHOSA interaction loss, MI355X — round 12: round-8 structure (68.8 us) +
// dwordx4 gather (r10) + HALF-K gather split. r11 showed longer gather blocks
// drift out of the stream-warmed L2 window (FETCH 185->290 MB, 103 us).
// This goes the opposite way: each (b,part) gather becomes TWO half-K blocks
// -> half the block duration (tighter temporal locality with the stream) and
// 2x gather TLP (smaller latency tail). Halves are folded in pair_kernel:
// min/max fold exact (mask bits identical); sum fold reorders (+~1e-8,
// threshold 3.16e-5).
constexpr int B_   = 256;
constexpr int NS_  = 10475;
constexpr int NO_  = 65536;
constexpr int P_   = 8;
constexpr int KS_  = 1024;
constexpr int KO_  = 2048;
constexpr int NBLK_S = 4;    // stream blocks per batch, smpl
constexpr int NBLK_O = 16;   // stream blocks per batch, object
constexpr float EPS_ = 1e-9f;
constexpr float ZTH_ = 5.0f;

// per-batch units: 16 objsum | 16 objgather-half | 4 smplsum | 16 smplgather-half
constexpr int GOH_ = 16;
constexpr int GSH_ = 16;
constexpr int UNITS_PER_B = NBLK_O + GOH_ + NBLK_S + GSH_;   // 52
constexpr int NXCD = 8;
constexpr int NSLOT = B_ / NXCD;                             // 32

// 16 B vector with 4 B alignment (emits global_load_dwordx4 from 12 B stride).
typedef float f32x4a4 __attribute__((ext_vector_type(4), aligned(4)));

#define DEV_INLINE __device__ __forceinline__

DEV_INLINE float wredsum(float v) {
#pragma unroll
    for (int o = 32; o; o >>= 1) v += __shfl_down(v, o);
    return v;
}
DEV_INLINE float wredmin(float v) {
#pragma unroll
    for (int o = 32; o; o >>= 1) v = fminf(v, __shfl_down(v, o));
    return v;
}
DEV_INLINE float wredmax(float v) {
#pragma unroll
    for (int o = 32; o; o >>= 1) v = fmaxf(v, __shfl_down(v, o));
    return v;
}

// ---------------------------------------------------------------------------
// Stream role: per-batch component partial sums (verbatim round-6/8).
// ---------------------------------------------------------------------------
template <int N, int NBLK>
DEV_INLINE void batch_sum_body(const float* __restrict__ v, int b, int blk,
                               float* __restrict__ out) {
    const int chunk = (N + NBLK - 1) / NBLK;
    const int s = blk * chunk;
    const int e = min(N, s + chunk);
    const float* base = v + (size_t)b * N * 3;
    float sx = 0.f, sy = 0.f, sz = 0.f;
    for (int i = s + (int)threadIdx.x; i < e; i += 256) {
        const float* p = base + (size_t)i * 3;
        sx += p[0];
        sy += p[1];
        sz += p[2];
    }
    __shared__ float red[3][4];
    float r0 = wredsum(sx), r1 = wredsum(sy), r2 = wredsum(sz);
    const int lane = threadIdx.x & 63, wv = threadIdx.x >> 6;
    if (lane == 0) { red[0][wv] = r0; red[1][wv] = r1; red[2][wv] = r2; }
    __syncthreads();
    if (threadIdx.x == 0) {
        float* o = out + ((size_t)b * NBLK + blk) * 3;
        o[0] = red[0][0] + red[0][1] + red[0][2] + red[0][3];
        o[1] = red[1][0] + red[1][1] + red[1][2] + red[1][3];
        o[2] = red[2][0] + red[2][1] + red[2][2] + red[2][3];
    }
}

// ---------------------------------------------------------------------------
// Gather role: HALF of one (batch,part) index list -> 9 half-stats.
// out record: halfstats[((b*P+p)*2 + h)*9 + q]. dwordx4 per vertex; the
// global-last vertex uses a shifted load + component select (r10).
// ---------------------------------------------------------------------------
template <int N, int K>
DEV_INLINE void part_stats_half_body(const float* __restrict__ v,
                                     const int* __restrict__ pidx,
                                     const float* __restrict__ Ks,
                                     int b, int p, int h,
                                     float* __restrict__ out) {
    const float fx = Ks[b * 9 + 0];
    const float cx = Ks[b * 9 + 2];
    const float fy = Ks[b * 9 + 4];
    const float cy = Ks[b * 9 + 5];
    const float* base = v + (size_t)b * N * 3;
    const int* idx = pidx + (size_t)p * K + (size_t)h * (K / 2);
    const bool lastBatch = (b == B_ - 1);

    constexpr int ITER = (K / 2) / 256;
    int ids[ITER];
#pragma unroll
    for (int j = 0; j < ITER; ++j) ids[j] = idx[threadIdx.x + j * 256];

    float vx[ITER], vy[ITER], vz[ITER];
#pragma unroll
    for (int j = 0; j < ITER; ++j) {
        const bool shift = lastBatch && (ids[j] == N - 1);
        const float* vp = base + (size_t)ids[j] * 3 - (shift ? 1 : 0);
        const f32x4a4 f = *reinterpret_cast<const f32x4a4*>(vp);
        vx[j] = shift ? f.y : f.x;
        vy[j] = shift ? f.z : f.y;
        vz[j] = shift ? f.w : f.z;
    }

    float umin = INFINITY, umax = -INFINITY, wmin = INFINITY, wmax = -INFINITY;
    float zmin = INFINITY, zmax = -INFINITY;
    float sx = 0.f, sy = 0.f, sz = 0.f;
#pragma unroll
    for (int j = 0; j < ITER; ++j) {
        const float x = vx[j], y = vy[j], z = vz[j];
        sx += x; sy += y; sz += z;
        zmin = fminf(zmin, z); zmax = fmaxf(zmax, z);
        float u, w;
        {
#pragma clang fp contract(off)
            const float zd = z + EPS_;
            const float x_ = x / zd;
            const float y_ = (-y) / zd;
            u = fx * x_ + cx;
            w = 1.0f - (fy * y_ + cy);
            u = 2.0f * (u - 0.5f);
            w = 2.0f * (w - 0.5f);
        }
        umin = fminf(umin, u); umax = fmaxf(umax, u);
        wmin = fminf(wmin, w); wmax = fmaxf(wmax, w);
    }

    __shared__ float red[4][9];
    float r[9];
    r[0] = wredmin(umin); r[1] = wredmax(umax);
    r[2] = wredmin(wmin); r[3] = wredmax(wmax);
    r[4] = wredmin(zmin); r[5] = wredmax(zmax);
    r[6] = wredsum(sx);   r[7] = wredsum(sy); r[8] = wredsum(sz);
    const int lane = threadIdx.x & 63, wv = threadIdx.x >> 6;
    if (lane == 0) {
#pragma unroll
        for (int q = 0; q < 9; ++q) red[wv][q] = r[q];
    }
    __syncthreads();
    if (threadIdx.x == 0) {
        float* o = out + (((size_t)b * P_ + p) * 2 + h) * 9;
        o[0] = fminf(fminf(red[0][0], red[1][0]), fminf(red[2][0], red[3][0]));
        o[1] = fmaxf(fmaxf(red[0][1], red[1][1]), fmaxf(red[2][1], red[3][1]));
        o[2] = fminf(fminf(red[0][2], red[1][2]), fminf(red[2][2], red[3][2]));
        o[3] = fmaxf(fmaxf(red[0][3], red[1][3]), fmaxf(red[2][3], red[3][3]));
        o[4] = fminf(fminf(red[0][4], red[1][4]), fminf(red[2][4], red[3][4]));
        o[5] = fmaxf(fmaxf(red[0][5], red[1][5]), fmaxf(red[2][5], red[3][5]));
        o[6] = red[0][6] + red[1][6] + red[2][6] + red[3][6];
        o[7] = red[0][7] + red[1][7] + red[2][7] + red[3][7];
        o[8] = red[0][8] + red[1][8] + red[2][8] + red[3][8];
    }
}

// ---------------------------------------------------------------------------
// Phase 1: gid -> xcd = gid&7, unit = gid>>3, slot = unit/52, role = unit%52.
// Stream roles: batch slot*8+xcd. Gather roles: previous slot's batch.
// role: [0,16) objsum | [16,32) objgather-half (p=(r-16)>>1, h=(r-16)&1)
//     | [32,36) smplsum | [36,52) smplgather-half.
// ---------------------------------------------------------------------------
__global__ __launch_bounds__(256) void phase1_kernel(
        const float* __restrict__ obj, const float* __restrict__ smpl,
        const float* __restrict__ Ks,
        const int* __restrict__ sidx, const int* __restrict__ oidx,
        float* __restrict__ sumO, float* __restrict__ sumS,
        float* __restrict__ halfO, float* __restrict__ halfS) {
    const int gid = blockIdx.x;
    const int xcd = gid & (NXCD - 1);
    const int unit = gid >> 3;
    const int slot = unit / UNITS_PER_B;
    const int role = unit % UNITS_PER_B;
    const int bs = slot * NXCD + xcd;                               // stream batch
    const int bg = ((slot + NSLOT - 1) & (NSLOT - 1)) * NXCD + xcd; // gather batch
    if (role < NBLK_O) {
        batch_sum_body<NO_, NBLK_O>(obj, bs, role, sumO);
    } else if (role < NBLK_O + GOH_) {
        const int r = role - NBLK_O;
        part_stats_half_body<NO_, KO_>(obj, oidx, Ks, bg, r >> 1, r & 1, halfO);
    } else if (role < NBLK_O + GOH_ + NBLK_S) {
        batch_sum_body<NS_, NBLK_S>(smpl, bs, role - (NBLK_O + GOH_), sumS);
    } else {
        const int r = role - (NBLK_O + GOH_ + NBLK_S);
        part_stats_half_body<NS_, KS_>(smpl, sidx, Ks, bg, r >> 1, r & 1, halfS);
    }
}

// ---------------------------------------------------------------------------
// Kernel D: fold half-stats, then per-batch pair masking + partial sums.
// Min/max fold is exact -> mask bits identical to rounds 1-10.
// ---------------------------------------------------------------------------
__global__ __launch_bounds__(64) void pair_kernel(
        const float* __restrict__ halfS, const float* __restrict__ halfO,
        float* __restrict__ partial) {
#pragma clang fp contract(off)
    const int b = blockIdx.x;
    __shared__ float sS[P_][9];
    __shared__ float sO[P_][9];
    const int t = threadIdx.x;
    for (int q = t; q < 2 * P_ * 9; q += 64) {
        const int tensor = q / (P_ * 9);
        const int r = q % (P_ * 9);
        const int p = r / 9, k = r % 9;
        const float* hsrc = (tensor == 0) ? halfS : halfO;
        const float h0 = hsrc[(((size_t)b * P_ + p) * 2 + 0) * 9 + k];
        const float h1 = hsrc[(((size_t)b * P_ + p) * 2 + 1) * 9 + k];
        float val;
        if (k == 0 || k == 2 || k == 4)      val = fminf(h0, h1);
        else if (k == 1 || k == 3 || k == 5) val = fmaxf(h0, h1);
        else                                 val = h0 + h1;
        if (tensor == 0) sS[p][k] = val; else sO[p][k] = val;
    }
    __syncthreads();

    const int ps = t >> 3;
    const int po = t & 7;

    const float* ssp = sS[po];
    const float* sop = sO[po];
    const float pcu = (ssp[0] + ssp[1]) * 0.5f;
    const float phu = (ssp[1] - ssp[0]) * 0.5f * 1.5f;
    const float pcw = (ssp[2] + ssp[3]) * 0.5f;
    const float phw = (ssp[3] - ssp[2]) * 0.5f * 1.5f;
    const float px0 = pcu - phu, px1 = pcu + phu;
    const float py0 = pcw - phw, py1 = pcw + phw;
    const float ocu = (sop[0] + sop[1]) * 0.5f;
    const float ohu = (sop[1] - sop[0]) * 0.5f * 1.5f;
    const float ocw = (sop[2] + sop[3]) * 0.5f;
    const float ohw = (sop[3] - sop[2]) * 0.5f * 1.5f;
    const float ox0 = ocu - ohu, ox1 = ocu + ohu;
    const float oy0 = ocw - ohw, oy1 = ocw + ohw;
    const bool ov = !((ox0 > px1) || (px0 > ox1) || (oy0 > py1) || (py0 > oy1));

    const float a  = sS[ps][4];
    const float bm = sS[ps][5];
    const float c  = sO[po][4];
    const float d  = sO[po][5];
    const float gap = fminf(fabsf(c - bm), fabsf(a - d));
    const float zd = ((d >= a) && (bm >= c)) ? 0.f : gap;
    const bool m = ov && (zd < ZTH_);

    const float ms0 = sS[ps][6] / (float)KS_;
    const float ms1 = sS[ps][7] / (float)KS_;
    const float ms2 = sS[ps][8] / (float)KS_;
    const float mo0 = sO[po][6] / (float)KO_;
    const float mo1 = sO[po][7] / (float)KO_;
    const float mo2 = sO[po][8] / (float)KO_;
    const float d0 = ms0 - mo0, d1 = ms1 - mo1, d2 = ms2 - mo2;
    const float pm = (d0 * d0 + d1 * d1 + d2 * d2) / 3.0f;

    float psum = m ? pm : 0.f;
    float pcnt = m ? 1.f : 0.f;
    psum = wredsum(psum);
    pcnt = wredsum(pcnt);
    if (t == 0) {
        partial[(size_t)b * 2 + 0] = psum;
        partial[(size_t)b * 2 + 1] = pcnt;
    }
}

// ---------------------------------------------------------------------------
// Kernel E: loss_inter + final reduce (verbatim round-6/8).
// ---------------------------------------------------------------------------
__global__ __launch_bounds__(256) void last_kernel(
        const float* __restrict__ sumS, const float* __restrict__ sumO,
        const float* __restrict__ pairPartial, float* __restrict__ out) {
    const int t = threadIdx.x;
    float d2 = 0.f;
#pragma unroll
    for (int c = 0; c < 3; ++c) {
        float ss = 0.f, so = 0.f;
#pragma unroll
        for (int k = 0; k < NBLK_S; ++k) ss += sumS[((size_t)t * NBLK_S + k) * 3 + c];
#pragma unroll
        for (int k = 0; k < NBLK_O; ++k) so += sumO[((size_t)t * NBLK_O + k) * 3 + c];
        const float ms = ss / (float)NS_;
        const float mo = so / (float)NO_;
        const float d = ms - mo;
        d2 += d * d;
    }
    float s = pairPartial[(size_t)t * 2 + 0];
    float c2 = pairPartial[(size_t)t * 2 + 1];
    __shared__ float rli[4], rs[4], rc[4];
    const float rl = wredsum(d2);
    const float ss2 = wredsum(s);
    const float cc = wredsum(c2);
    const int lane = t & 63, wv = t >> 6;
    if (lane == 0) { rli[wv] = rl; rs[wv] = ss2; rc[wv] = cc; }
    __syncthreads();
    if (t == 0) {
        const float tot = rli[0] + rli[1] + rli[2] + rli[3];
        out[0] = tot / (3.0f * (float)B_) / (float)B_;
        const float S = rs[0] + rs[1] + rs[2] + rs[3];
        const float C = rc[0] + rc[1] + rc[2] + rc[3];
        out[1] = (C > 0.f) ? (S / C) : 0.f;
    }
}

// ---------------------------------------------------------------------------
extern "C" void kernel_launch(void* const* d_in, const int* in_sizes, int n_in,
                              void* d_out, int out_size, void* d_ws, size_t ws_size,
                              hipStream_t stream) {
    const float* smpl = (const float*)d_in[0];
    const float* obj  = (const float*)d_in[1];
    const float* Ks   = (const float*)d_in[2];
    const int*   sidx = (const int*)d_in[3];
    const int*   oidx = (const int*)d_in[4];
    float* out = (float*)d_out;

    float* w = (float*)d_ws;
    float* sumO  = w;                                  // 256*16*3 = 12288
    float* sumS  = sumO + (size_t)B_ * NBLK_O * 3;     // 256*4*3  = 3072
    float* halfS = sumS + (size_t)B_ * NBLK_S * 3;     // 256*8*2*9 = 36864
    float* halfO = halfS + (size_t)B_ * P_ * 2 * 9;    // 256*8*2*9 = 36864
    float* pairP = halfO + (size_t)B_ * P_ * 2 * 9;    // 512

    phase1_kernel<<<B_ * UNITS_PER_B, 256, 0, stream>>>(
        obj, smpl, Ks, sidx, oidx, sumO, sumS, halfO, halfS);
    pair_kernel<<<B_, 64, 0, stream>>>(halfS, halfO, pairP);
    last_kernel<<<1, 256, 0, stream>>>(sumS, sumO, pairP, out);
}

// Round 13
// 63.733 us; speedup vs baseline: 1.6211x; 1.0026x over previous
//
#include <hip/hip_runtime.h>
#include <math.h>

// PHOSA interaction loss, MI355X — round 13: continue r12's winning direction.
// r12 (half-K gather split): 68.8 -> 63.9 us, FETCH 185 -> 150 MB. Shorter
// gather blocks stay inside the stream-warmed L2/L3 window and add TLP.
// r13: object gathers split into QUARTERS (32 blocks/batch, ITER=2/thread);
// smpl stays at halves (quarter would be pure reduction overhead).
// Quarter/half records folded in pair_kernel: min/max fold exact (mask bits
// identical); sum fold reorders (+~1e-8 vs 3.16e-5 threshold).
constexpr int B_   = 256;
constexpr int NS_  = 10475;
constexpr int NO_  = 65536;
constexpr int P_   = 8;
constexpr int KS_  = 1024;
constexpr int KO_  = 2048;
constexpr int NBLK_S = 4;    // stream blocks per batch, smpl
constexpr int NBLK_O = 16;   // stream blocks per batch, object
constexpr int DIVO_ = 4;     // obj gather split
constexpr int DIVS_ = 2;     // smpl gather split
constexpr float EPS_ = 1e-9f;
constexpr float ZTH_ = 5.0f;

// per-batch units: 16 objsum | 32 objgather-qtr | 4 smplsum | 16 smplgather-half
constexpr int GO_ = P_ * DIVO_;                          // 32
constexpr int GS_ = P_ * DIVS_;                          // 16
constexpr int UNITS_PER_B = NBLK_O + GO_ + NBLK_S + GS_; // 68
constexpr int NXCD = 8;
constexpr int NSLOT = B_ / NXCD;                         // 32

// 16 B vector with 4 B alignment (emits global_load_dwordx4 from 12 B stride).
typedef float f32x4a4 __attribute__((ext_vector_type(4), aligned(4)));

#define DEV_INLINE __device__ __forceinline__

DEV_INLINE float wredsum(float v) {
#pragma unroll
    for (int o = 32; o; o >>= 1) v += __shfl_down(v, o);
    return v;
}
DEV_INLINE float wredmin(float v) {
#pragma unroll
    for (int o = 32; o; o >>= 1) v = fminf(v, __shfl_down(v, o));
    return v;
}
DEV_INLINE float wredmax(float v) {
#pragma unroll
    for (int o = 32; o; o >>= 1) v = fmaxf(v, __shfl_down(v, o));
    return v;
}

// ---------------------------------------------------------------------------
// Stream role: per-batch component partial sums (verbatim round-6/8/12).
// ---------------------------------------------------------------------------
template <int N, int NBLK>
DEV_INLINE void batch_sum_body(const float* __restrict__ v, int b, int blk,
                               float* __restrict__ out) {
    const int chunk = (N + NBLK - 1) / NBLK;
    const int s = blk * chunk;
    const int e = min(N, s + chunk);
    const float* base = v + (size_t)b * N * 3;
    float sx = 0.f, sy = 0.f, sz = 0.f;
    for (int i = s + (int)threadIdx.x; i < e; i += 256) {
        const float* p = base + (size_t)i * 3;
        sx += p[0];
        sy += p[1];
        sz += p[2];
    }
    __shared__ float red[3][4];
    float r0 = wredsum(sx), r1 = wredsum(sy), r2 = wredsum(sz);
    const int lane = threadIdx.x & 63, wv = threadIdx.x >> 6;
    if (lane == 0) { red[0][wv] = r0; red[1][wv] = r1; red[2][wv] = r2; }
    __syncthreads();
    if (threadIdx.x == 0) {
        float* o = out + ((size_t)b * NBLK + blk) * 3;
        o[0] = red[0][0] + red[0][1] + red[0][2] + red[0][3];
        o[1] = red[1][0] + red[1][1] + red[1][2] + red[1][3];
        o[2] = red[2][0] + red[2][1] + red[2][2] + red[2][3];
    }
}

// ---------------------------------------------------------------------------
// Gather role: 1/DIV of one (batch,part) index list -> 9 split-stats.
// out record: split[((b*P+p)*DIV + h)*9 + q]. dwordx4 per vertex; the
// global-last vertex uses a shifted load + component select (r10).
// ---------------------------------------------------------------------------
template <int N, int K, int DIV>
DEV_INLINE void part_stats_split_body(const float* __restrict__ v,
                                      const int* __restrict__ pidx,
                                      const float* __restrict__ Ks,
                                      int b, int p, int h,
                                      float* __restrict__ out) {
    const float fx = Ks[b * 9 + 0];
    const float cx = Ks[b * 9 + 2];
    const float fy = Ks[b * 9 + 4];
    const float cy = Ks[b * 9 + 5];
    const float* base = v + (size_t)b * N * 3;
    const int* idx = pidx + (size_t)p * K + (size_t)h * (K / DIV);
    const bool lastBatch = (b == B_ - 1);

    constexpr int ITER = (K / DIV) / 256;
    int ids[ITER];
#pragma unroll
    for (int j = 0; j < ITER; ++j) ids[j] = idx[threadIdx.x + j * 256];

    float vx[ITER], vy[ITER], vz[ITER];
#pragma unroll
    for (int j = 0; j < ITER; ++j) {
        const bool shift = lastBatch && (ids[j] == N - 1);
        const float* vp = base + (size_t)ids[j] * 3 - (shift ? 1 : 0);
        const f32x4a4 f = *reinterpret_cast<const f32x4a4*>(vp);
        vx[j] = shift ? f.y : f.x;
        vy[j] = shift ? f.z : f.y;
        vz[j] = shift ? f.w : f.z;
    }

    float umin = INFINITY, umax = -INFINITY, wmin = INFINITY, wmax = -INFINITY;
    float zmin = INFINITY, zmax = -INFINITY;
    float sx = 0.f, sy = 0.f, sz = 0.f;
#pragma unroll
    for (int j = 0; j < ITER; ++j) {
        const float x = vx[j], y = vy[j], z = vz[j];
        sx += x; sy += y; sz += z;
        zmin = fminf(zmin, z); zmax = fmaxf(zmax, z);
        float u, w;
        {
#pragma clang fp contract(off)
            const float zd = z + EPS_;
            const float x_ = x / zd;
            const float y_ = (-y) / zd;
            u = fx * x_ + cx;
            w = 1.0f - (fy * y_ + cy);
            u = 2.0f * (u - 0.5f);
            w = 2.0f * (w - 0.5f);
        }
        umin = fminf(umin, u); umax = fmaxf(umax, u);
        wmin = fminf(wmin, w); wmax = fmaxf(wmax, w);
    }

    __shared__ float red[4][9];
    float r[9];
    r[0] = wredmin(umin); r[1] = wredmax(umax);
    r[2] = wredmin(wmin); r[3] = wredmax(wmax);
    r[4] = wredmin(zmin); r[5] = wredmax(zmax);
    r[6] = wredsum(sx);   r[7] = wredsum(sy); r[8] = wredsum(sz);
    const int lane = threadIdx.x & 63, wv = threadIdx.x >> 6;
    if (lane == 0) {
#pragma unroll
        for (int q = 0; q < 9; ++q) red[wv][q] = r[q];
    }
    __syncthreads();
    if (threadIdx.x == 0) {
        float* o = out + (((size_t)b * P_ + p) * DIV + h) * 9;
        o[0] = fminf(fminf(red[0][0], red[1][0]), fminf(red[2][0], red[3][0]));
        o[1] = fmaxf(fmaxf(red[0][1], red[1][1]), fmaxf(red[2][1], red[3][1]));
        o[2] = fminf(fminf(red[0][2], red[1][2]), fminf(red[2][2], red[3][2]));
        o[3] = fmaxf(fmaxf(red[0][3], red[1][3]), fmaxf(red[2][3], red[3][3]));
        o[4] = fminf(fminf(red[0][4], red[1][4]), fminf(red[2][4], red[3][4]));
        o[5] = fmaxf(fmaxf(red[0][5], red[1][5]), fmaxf(red[2][5], red[3][5]));
        o[6] = red[0][6] + red[1][6] + red[2][6] + red[3][6];
        o[7] = red[0][7] + red[1][7] + red[2][7] + red[3][7];
        o[8] = red[0][8] + red[1][8] + red[2][8] + red[3][8];
    }
}

// ---------------------------------------------------------------------------
// Phase 1: gid -> xcd = gid&7, unit = gid>>3, slot = unit/68, role = unit%68.
// Stream roles: batch slot*8+xcd. Gather roles: previous slot's batch.
// role: [0,16) objsum | [16,48) objgather-qtr (p=(r)>>2, h=r&3)
//     | [48,52) smplsum | [52,68) smplgather-half (p=r>>1, h=r&1).
// ---------------------------------------------------------------------------
__global__ __launch_bounds__(256) void phase1_kernel(
        const float* __restrict__ obj, const float* __restrict__ smpl,
        const float* __restrict__ Ks,
        const int* __restrict__ sidx, const int* __restrict__ oidx,
        float* __restrict__ sumO, float* __restrict__ sumS,
        float* __restrict__ splitO, float* __restrict__ splitS) {
    const int gid = blockIdx.x;
    const int xcd = gid & (NXCD - 1);
    const int unit = gid >> 3;
    const int slot = unit / UNITS_PER_B;
    const int role = unit % UNITS_PER_B;
    const int bs = slot * NXCD + xcd;                               // stream batch
    const int bg = ((slot + NSLOT - 1) & (NSLOT - 1)) * NXCD + xcd; // gather batch
    if (role < NBLK_O) {
        batch_sum_body<NO_, NBLK_O>(obj, bs, role, sumO);
    } else if (role < NBLK_O + GO_) {
        const int r = role - NBLK_O;
        part_stats_split_body<NO_, KO_, DIVO_>(obj, oidx, Ks, bg,
                                               r >> 2, r & 3, splitO);
    } else if (role < NBLK_O + GO_ + NBLK_S) {
        batch_sum_body<NS_, NBLK_S>(smpl, bs, role - (NBLK_O + GO_), sumS);
    } else {
        const int r = role - (NBLK_O + GO_ + NBLK_S);
        part_stats_split_body<NS_, KS_, DIVS_>(smpl, sidx, Ks, bg,
                                               r >> 1, r & 1, splitS);
    }
}

// ---------------------------------------------------------------------------
// Kernel D: fold split-stats, then per-batch pair masking + partial sums.
// Min/max fold exact -> mask bits identical to rounds 1-12.
// ---------------------------------------------------------------------------
__global__ __launch_bounds__(64) void pair_kernel(
        const float* __restrict__ splitS, const float* __restrict__ splitO,
        float* __restrict__ partial) {
#pragma clang fp contract(off)
    const int b = blockIdx.x;
    __shared__ float sS[P_][9];
    __shared__ float sO[P_][9];
    const int t = threadIdx.x;
    for (int q = t; q < 2 * P_ * 9; q += 64) {
        const int tensor = q / (P_ * 9);
        const int r = q % (P_ * 9);
        const int p = r / 9, k = r % 9;
        const float* hsrc = (tensor == 0) ? splitS : splitO;
        const int div = (tensor == 0) ? DIVS_ : DIVO_;
        float val = hsrc[(((size_t)b * P_ + p) * div + 0) * 9 + k];
        for (int h = 1; h < div; ++h) {
            const float hv = hsrc[(((size_t)b * P_ + p) * div + h) * 9 + k];
            if (k == 0 || k == 2 || k == 4)      val = fminf(val, hv);
            else if (k == 1 || k == 3 || k == 5) val = fmaxf(val, hv);
            else                                 val = val + hv;
        }
        if (tensor == 0) sS[p][k] = val; else sO[p][k] = val;
    }
    __syncthreads();

    const int ps = t >> 3;
    const int po = t & 7;

    const float* ssp = sS[po];
    const float* sop = sO[po];
    const float pcu = (ssp[0] + ssp[1]) * 0.5f;
    const float phu = (ssp[1] - ssp[0]) * 0.5f * 1.5f;
    const float pcw = (ssp[2] + ssp[3]) * 0.5f;
    const float phw = (ssp[3] - ssp[2]) * 0.5f * 1.5f;
    const float px0 = pcu - phu, px1 = pcu + phu;
    const float py0 = pcw - phw, py1 = pcw + phw;
    const float ocu = (sop[0] + sop[1]) * 0.5f;
    const float ohu = (sop[1] - sop[0]) * 0.5f * 1.5f;
    const float ocw = (sop[2] + sop[3]) * 0.5f;
    const float ohw = (sop[3] - sop[2]) * 0.5f * 1.5f;
    const float ox0 = ocu - ohu, ox1 = ocu + ohu;
    const float oy0 = ocw - ohw, oy1 = ocw + ohw;
    const bool ov = !((ox0 > px1) || (px0 > ox1) || (oy0 > py1) || (py0 > oy1));

    const float a  = sS[ps][4];
    const float bm = sS[ps][5];
    const float c  = sO[po][4];
    const float d  = sO[po][5];
    const float gap = fminf(fabsf(c - bm), fabsf(a - d));
    const float zd = ((d >= a) && (bm >= c)) ? 0.f : gap;
    const bool m = ov && (zd < ZTH_);

    const float ms0 = sS[ps][6] / (float)KS_;
    const float ms1 = sS[ps][7] / (float)KS_;
    const float ms2 = sS[ps][8] / (float)KS_;
    const float mo0 = sO[po][6] / (float)KO_;
    const float mo1 = sO[po][7] / (float)KO_;
    const float mo2 = sO[po][8] / (float)KO_;
    const float d0 = ms0 - mo0, d1 = ms1 - mo1, d2 = ms2 - mo2;
    const float pm = (d0 * d0 + d1 * d1 + d2 * d2) / 3.0f;

    float psum = m ? pm : 0.f;
    float pcnt = m ? 1.f : 0.f;
    psum = wredsum(psum);
    pcnt = wredsum(pcnt);
    if (t == 0) {
        partial[(size_t)b * 2 + 0] = psum;
        partial[(size_t)b * 2 + 1] = pcnt;
    }
}

// ---------------------------------------------------------------------------
// Kernel E: loss_inter + final reduce (verbatim round-6/8/12).
// ---------------------------------------------------------------------------
__global__ __launch_bounds__(256) void last_kernel(
        const float* __restrict__ sumS, const float* __restrict__ sumO,
        const float* __restrict__ pairPartial, float* __restrict__ out) {
    const int t = threadIdx.x;
    float d2 = 0.f;
#pragma unroll
    for (int c = 0; c < 3; ++c) {
        float ss = 0.f, so = 0.f;
#pragma unroll
        for (int k = 0; k < NBLK_S; ++k) ss += sumS[((size_t)t * NBLK_S + k) * 3 + c];
#pragma unroll
        for (int k = 0; k < NBLK_O; ++k) so += sumO[((size_t)t * NBLK_O + k) * 3 + c];
        const float ms = ss / (float)NS_;
        const float mo = so / (float)NO_;
        const float d = ms - mo;
        d2 += d * d;
    }
    float s = pairPartial[(size_t)t * 2 + 0];
    float c2 = pairPartial[(size_t)t * 2 + 1];
    __shared__ float rli[4], rs[4], rc[4];
    const float rl = wredsum(d2);
    const float ss2 = wredsum(s);
    const float cc = wredsum(c2);
    const int lane = t & 63, wv = t >> 6;
    if (lane == 0) { rli[wv] = rl; rs[wv] = ss2; rc[wv] = cc; }
    __syncthreads();
    if (t == 0) {
        const float tot = rli[0] + rli[1] + rli[2] + rli[3];
        out[0] = tot / (3.0f * (float)B_) / (float)B_;
        const float S = rs[0] + rs[1] + rs[2] + rs[3];
        const float C = rc[0] + rc[1] + rc[2] + rc[3];
        out[1] = (C > 0.f) ? (S / C) : 0.f;
    }
}

// ---------------------------------------------------------------------------
extern "C" void kernel_launch(void* const* d_in, const int* in_sizes, int n_in,
                              void* d_out, int out_size, void* d_ws, size_t ws_size,
                              hipStream_t stream) {
    const float* smpl = (const float*)d_in[0];
    const float* obj  = (const float*)d_in[1];
    const float* Ks   = (const float*)d_in[2];
    const int*   sidx = (const int*)d_in[3];
    const int*   oidx = (const int*)d_in[4];
    float* out = (float*)d_out;

    float* w = (float*)d_ws;
    float* sumO   = w;                                     // 256*16*3 = 12288
    float* sumS   = sumO + (size_t)B_ * NBLK_O * 3;        // 256*4*3  = 3072
    float* splitS = sumS + (size_t)B_ * NBLK_S * 3;        // 256*8*2*9 = 36864
    float* splitO = splitS + (size_t)B_ * P_ * DIVS_ * 9;  // 256*8*4*9 = 73728
    float* pairP  = splitO + (size_t)B_ * P_ * DIVO_ * 9;  // 512

    phase1_kernel<<<B_ * UNITS_PER_B, 256, 0, stream>>>(
        obj, smpl, Ks, sidx, oidx, sumO, sumS, splitO, splitS);
    pair_kernel<<<B_, 64, 0, stream>>>(splitS, splitO, pairP);
    last_kernel<<<1, 256, 0, stream>>>(sumS, sumO, pairP, out);
}

// Round 14
// 62.106 us; speedup vs baseline: 1.6636x; 1.0262x over previous
//
#include <hip/hip_runtime.h>
#include <math.h>

// PHOSA interaction loss, MI355X — round 14: r13 (split gathers, 63.7 us)
// + r9's float4 object stream. TA model: scalar 3x-dword streaming touches
// each 64 B segment 3x per wave-iteration (9.4 M TA cycles for obj stream);
// float4 touches each segment once (3.1 M). Gathers (6.3 M TA cycles,
// irreducible) are already dwordx4. r9 proved the float4 grouping keeps
// absmax 0.0; r9's mild regression was against the pre-split structure where
// long gather blocks were the limiter (fixed in r12).
constexpr int B_   = 256;
constexpr int NS_  = 10475;
constexpr int NO_  = 65536;
constexpr int P_   = 8;
constexpr int KS_  = 1024;
constexpr int KO_  = 2048;
constexpr int NBLK_S = 4;    // stream blocks per batch, smpl
constexpr int NBLK_O = 16;   // stream blocks per batch, object (4096 verts)
constexpr int DIVO_ = 4;     // obj gather split
constexpr int DIVS_ = 2;     // smpl gather split
constexpr float EPS_ = 1e-9f;
constexpr float ZTH_ = 5.0f;

// per-batch units: 16 objsum | 32 objgather-qtr | 4 smplsum | 16 smplgather-half
constexpr int GO_ = P_ * DIVO_;                          // 32
constexpr int GS_ = P_ * DIVS_;                          // 16
constexpr int UNITS_PER_B = NBLK_O + GO_ + NBLK_S + GS_; // 68
constexpr int NXCD = 8;
constexpr int NSLOT = B_ / NXCD;                         // 32

// 16 B vector with 4 B alignment (emits global_load_dwordx4 from 12 B stride).
typedef float f32x4a4 __attribute__((ext_vector_type(4), aligned(4)));

#define DEV_INLINE __device__ __forceinline__

DEV_INLINE float wredsum(float v) {
#pragma unroll
    for (int o = 32; o; o >>= 1) v += __shfl_down(v, o);
    return v;
}
DEV_INLINE float wredmin(float v) {
#pragma unroll
    for (int o = 32; o; o >>= 1) v = fminf(v, __shfl_down(v, o));
    return v;
}
DEV_INLINE float wredmax(float v) {
#pragma unroll
    for (int o = 32; o; o >>= 1) v = fmaxf(v, __shfl_down(v, o));
    return v;
}

// ---------------------------------------------------------------------------
// Object stream role: float4-vectorized batch partial sums (verbatim r9).
// Chunk = 4096 verts = 3072 float4; 256 threads x 12 float4.
// Thread t, iter j handles 4-vertex group g = j*256 + t:
//   f0=(x0,y0,z0,x1) f1=(y1,z1,x2,y2) f2=(z2,x3,y3,z3).
// ---------------------------------------------------------------------------
DEV_INLINE void batch_sum_obj_body(const float* __restrict__ v, int b, int blk,
                                   float* __restrict__ out) {
    const float4* base = reinterpret_cast<const float4*>(
        v + (size_t)b * NO_ * 3 + (size_t)blk * 4096 * 3);
    const int t = threadIdx.x;
    float4 f[12];
#pragma unroll
    for (int j = 0; j < 4; ++j) {
        const int g = j * 256 + t;
#pragma unroll
        for (int q = 0; q < 3; ++q) f[j * 3 + q] = base[g * 3 + q];
    }
    float sx = 0.f, sy = 0.f, sz = 0.f;
#pragma unroll
    for (int j = 0; j < 4; ++j) {
        const float4 f0 = f[j * 3 + 0], f1 = f[j * 3 + 1], f2 = f[j * 3 + 2];
        sx += f0.x + f0.w + f1.z + f2.y;
        sy += f0.y + f1.x + f1.w + f2.z;
        sz += f0.z + f1.y + f2.x + f2.w;
    }
    __shared__ float red[3][4];
    const float r0 = wredsum(sx), r1 = wredsum(sy), r2 = wredsum(sz);
    const int lane = t & 63, wv = t >> 6;
    if (lane == 0) { red[0][wv] = r0; red[1][wv] = r1; red[2][wv] = r2; }
    __syncthreads();
    if (t == 0) {
        float* o = out + ((size_t)b * NBLK_O + blk) * 3;
        o[0] = red[0][0] + red[0][1] + red[0][2] + red[0][3];
        o[1] = red[1][0] + red[1][1] + red[1][2] + red[1][3];
        o[2] = red[2][0] + red[2][1] + red[2][2] + red[2][3];
    }
}

// ---------------------------------------------------------------------------
// smpl stream role: scalar partial sums (verbatim round-6/8/12/13).
// ---------------------------------------------------------------------------
DEV_INLINE void batch_sum_smpl_body(const float* __restrict__ v, int b, int blk,
                                    float* __restrict__ out) {
    constexpr int chunk = (NS_ + NBLK_S - 1) / NBLK_S;
    const int s = blk * chunk;
    const int e = min(NS_, s + chunk);
    const float* base = v + (size_t)b * NS_ * 3;
    float sx = 0.f, sy = 0.f, sz = 0.f;
    for (int i = s + (int)threadIdx.x; i < e; i += 256) {
        const float* p = base + (size_t)i * 3;
        sx += p[0];
        sy += p[1];
        sz += p[2];
    }
    __shared__ float red[3][4];
    float r0 = wredsum(sx), r1 = wredsum(sy), r2 = wredsum(sz);
    const int lane = threadIdx.x & 63, wv = threadIdx.x >> 6;
    if (lane == 0) { red[0][wv] = r0; red[1][wv] = r1; red[2][wv] = r2; }
    __syncthreads();
    if (threadIdx.x == 0) {
        float* o = out + ((size_t)b * NBLK_S + blk) * 3;
        o[0] = red[0][0] + red[0][1] + red[0][2] + red[0][3];
        o[1] = red[1][0] + red[1][1] + red[1][2] + red[1][3];
        o[2] = red[2][0] + red[2][1] + red[2][2] + red[2][3];
    }
}

// ---------------------------------------------------------------------------
// Gather role: 1/DIV of one (batch,part) index list -> 9 split-stats
// (verbatim r13). dwordx4 per vertex; global-last vertex shifted (r10).
// ---------------------------------------------------------------------------
template <int N, int K, int DIV>
DEV_INLINE void part_stats_split_body(const float* __restrict__ v,
                                      const int* __restrict__ pidx,
                                      const float* __restrict__ Ks,
                                      int b, int p, int h,
                                      float* __restrict__ out) {
    const float fx = Ks[b * 9 + 0];
    const float cx = Ks[b * 9 + 2];
    const float fy = Ks[b * 9 + 4];
    const float cy = Ks[b * 9 + 5];
    const float* base = v + (size_t)b * N * 3;
    const int* idx = pidx + (size_t)p * K + (size_t)h * (K / DIV);
    const bool lastBatch = (b == B_ - 1);

    constexpr int ITER = (K / DIV) / 256;
    int ids[ITER];
#pragma unroll
    for (int j = 0; j < ITER; ++j) ids[j] = idx[threadIdx.x + j * 256];

    float vx[ITER], vy[ITER], vz[ITER];
#pragma unroll
    for (int j = 0; j < ITER; ++j) {
        const bool shift = lastBatch && (ids[j] == N - 1);
        const float* vp = base + (size_t)ids[j] * 3 - (shift ? 1 : 0);
        const f32x4a4 f = *reinterpret_cast<const f32x4a4*>(vp);
        vx[j] = shift ? f.y : f.x;
        vy[j] = shift ? f.z : f.y;
        vz[j] = shift ? f.w : f.z;
    }

    float umin = INFINITY, umax = -INFINITY, wmin = INFINITY, wmax = -INFINITY;
    float zmin = INFINITY, zmax = -INFINITY;
    float sx = 0.f, sy = 0.f, sz = 0.f;
#pragma unroll
    for (int j = 0; j < ITER; ++j) {
        const float x = vx[j], y = vy[j], z = vz[j];
        sx += x; sy += y; sz += z;
        zmin = fminf(zmin, z); zmax = fmaxf(zmax, z);
        float u, w;
        {
#pragma clang fp contract(off)
            const float zd = z + EPS_;
            const float x_ = x / zd;
            const float y_ = (-y) / zd;
            u = fx * x_ + cx;
            w = 1.0f - (fy * y_ + cy);
            u = 2.0f * (u - 0.5f);
            w = 2.0f * (w - 0.5f);
        }
        umin = fminf(umin, u); umax = fmaxf(umax, u);
        wmin = fminf(wmin, w); wmax = fmaxf(wmax, w);
    }

    __shared__ float red[4][9];
    float r[9];
    r[0] = wredmin(umin); r[1] = wredmax(umax);
    r[2] = wredmin(wmin); r[3] = wredmax(wmax);
    r[4] = wredmin(zmin); r[5] = wredmax(zmax);
    r[6] = wredsum(sx);   r[7] = wredsum(sy); r[8] = wredsum(sz);
    const int lane = threadIdx.x & 63, wv = threadIdx.x >> 6;
    if (lane == 0) {
#pragma unroll
        for (int q = 0; q < 9; ++q) red[wv][q] = r[q];
    }
    __syncthreads();
    if (threadIdx.x == 0) {
        float* o = out + (((size_t)b * P_ + p) * DIV + h) * 9;
        o[0] = fminf(fminf(red[0][0], red[1][0]), fminf(red[2][0], red[3][0]));
        o[1] = fmaxf(fmaxf(red[0][1], red[1][1]), fmaxf(red[2][1], red[3][1]));
        o[2] = fminf(fminf(red[0][2], red[1][2]), fminf(red[2][2], red[3][2]));
        o[3] = fmaxf(fmaxf(red[0][3], red[1][3]), fmaxf(red[2][3], red[3][3]));
        o[4] = fminf(fminf(red[0][4], red[1][4]), fminf(red[2][4], red[3][4]));
        o[5] = fmaxf(fmaxf(red[0][5], red[1][5]), fmaxf(red[2][5], red[3][5]));
        o[6] = red[0][6] + red[1][6] + red[2][6] + red[3][6];
        o[7] = red[0][7] + red[1][7] + red[2][7] + red[3][7];
        o[8] = red[0][8] + red[1][8] + red[2][8] + red[3][8];
    }
}

// ---------------------------------------------------------------------------
// Phase 1: gid -> xcd = gid&7, unit = gid>>3, slot = unit/68, role = unit%68.
// Stream roles: batch slot*8+xcd. Gather roles: previous slot's batch.
// role: [0,16) objsum | [16,48) objgather-qtr (p=r>>2, h=r&3)
//     | [48,52) smplsum | [52,68) smplgather-half (p=r>>1, h=r&1).
// ---------------------------------------------------------------------------
__global__ __launch_bounds__(256) void phase1_kernel(
        const float* __restrict__ obj, const float* __restrict__ smpl,
        const float* __restrict__ Ks,
        const int* __restrict__ sidx, const int* __restrict__ oidx,
        float* __restrict__ sumO, float* __restrict__ sumS,
        float* __restrict__ splitO, float* __restrict__ splitS) {
    const int gid = blockIdx.x;
    const int xcd = gid & (NXCD - 1);
    const int unit = gid >> 3;
    const int slot = unit / UNITS_PER_B;
    const int role = unit % UNITS_PER_B;
    const int bs = slot * NXCD + xcd;                               // stream batch
    const int bg = ((slot + NSLOT - 1) & (NSLOT - 1)) * NXCD + xcd; // gather batch
    if (role < NBLK_O) {
        batch_sum_obj_body(obj, bs, role, sumO);
    } else if (role < NBLK_O + GO_) {
        const int r = role - NBLK_O;
        part_stats_split_body<NO_, KO_, DIVO_>(obj, oidx, Ks, bg,
                                               r >> 2, r & 3, splitO);
    } else if (role < NBLK_O + GO_ + NBLK_S) {
        batch_sum_smpl_body(smpl, bs, role - (NBLK_O + GO_), sumS);
    } else {
        const int r = role - (NBLK_O + GO_ + NBLK_S);
        part_stats_split_body<NS_, KS_, DIVS_>(smpl, sidx, Ks, bg,
                                               r >> 1, r & 1, splitS);
    }
}

// ---------------------------------------------------------------------------
// Kernel D: fold split-stats, then per-batch pair masking + partial sums
// (verbatim r13). Min/max fold exact -> mask bits identical.
// ---------------------------------------------------------------------------
__global__ __launch_bounds__(64) void pair_kernel(
        const float* __restrict__ splitS, const float* __restrict__ splitO,
        float* __restrict__ partial) {
#pragma clang fp contract(off)
    const int b = blockIdx.x;
    __shared__ float sS[P_][9];
    __shared__ float sO[P_][9];
    const int t = threadIdx.x;
    for (int q = t; q < 2 * P_ * 9; q += 64) {
        const int tensor = q / (P_ * 9);
        const int r = q % (P_ * 9);
        const int p = r / 9, k = r % 9;
        const float* hsrc = (tensor == 0) ? splitS : splitO;
        const int div = (tensor == 0) ? DIVS_ : DIVO_;
        float val = hsrc[(((size_t)b * P_ + p) * div + 0) * 9 + k];
        for (int h = 1; h < div; ++h) {
            const float hv = hsrc[(((size_t)b * P_ + p) * div + h) * 9 + k];
            if (k == 0 || k == 2 || k == 4)      val = fminf(val, hv);
            else if (k == 1 || k == 3 || k == 5) val = fmaxf(val, hv);
            else                                 val = val + hv;
        }
        if (tensor == 0) sS[p][k] = val; else sO[p][k] = val;
    }
    __syncthreads();

    const int ps = t >> 3;
    const int po = t & 7;

    const float* ssp = sS[po];
    const float* sop = sO[po];
    const float pcu = (ssp[0] + ssp[1]) * 0.5f;
    const float phu = (ssp[1] - ssp[0]) * 0.5f * 1.5f;
    const float pcw = (ssp[2] + ssp[3]) * 0.5f;
    const float phw = (ssp[3] - ssp[2]) * 0.5f * 1.5f;
    const float px0 = pcu - phu, px1 = pcu + phu;
    const float py0 = pcw - phw, py1 = pcw + phw;
    const float ocu = (sop[0] + sop[1]) * 0.5f;
    const float ohu = (sop[1] - sop[0]) * 0.5f * 1.5f;
    const float ocw = (sop[2] + sop[3]) * 0.5f;
    const float ohw = (sop[3] - sop[2]) * 0.5f * 1.5f;
    const float ox0 = ocu - ohu, ox1 = ocu + ohu;
    const float oy0 = ocw - ohw, oy1 = ocw + ohw;
    const bool ov = !((ox0 > px1) || (px0 > ox1) || (oy0 > py1) || (py0 > oy1));

    const float a  = sS[ps][4];
    const float bm = sS[ps][5];
    const float c  = sO[po][4];
    const float d  = sO[po][5];
    const float gap = fminf(fabsf(c - bm), fabsf(a - d));
    const float zd = ((d >= a) && (bm >= c)) ? 0.f : gap;
    const bool m = ov && (zd < ZTH_);

    const float ms0 = sS[ps][6] / (float)KS_;
    const float ms1 = sS[ps][7] / (float)KS_;
    const float ms2 = sS[ps][8] / (float)KS_;
    const float mo0 = sO[po][6] / (float)KO_;
    const float mo1 = sO[po][7] / (float)KO_;
    const float mo2 = sO[po][8] / (float)KO_;
    const float d0 = ms0 - mo0, d1 = ms1 - mo1, d2 = ms2 - mo2;
    const float pm = (d0 * d0 + d1 * d1 + d2 * d2) / 3.0f;

    float psum = m ? pm : 0.f;
    float pcnt = m ? 1.f : 0.f;
    psum = wredsum(psum);
    pcnt = wredsum(pcnt);
    if (t == 0) {
        partial[(size_t)b * 2 + 0] = psum;
        partial[(size_t)b * 2 + 1] = pcnt;
    }
}

// ---------------------------------------------------------------------------
// Kernel E: loss_inter + final reduce (verbatim round-6/8/12/13).
// ---------------------------------------------------------------------------
__global__ __launch_bounds__(256) void last_kernel(
        const float* __restrict__ sumS, const float* __restrict__ sumO,
        const float* __restrict__ pairPartial, float* __restrict__ out) {
    const int t = threadIdx.x;
    float d2 = 0.f;
#pragma unroll
    for (int c = 0; c < 3; ++c) {
        float ss = 0.f, so = 0.f;
#pragma unroll
        for (int k = 0; k < NBLK_S; ++k) ss += sumS[((size_t)t * NBLK_S + k) * 3 + c];
#pragma unroll
        for (int k = 0; k < NBLK_O; ++k) so += sumO[((size_t)t * NBLK_O + k) * 3 + c];
        const float ms = ss / (float)NS_;
        const float mo = so / (float)NO_;
        const float d = ms - mo;
        d2 += d * d;
    }
    float s = pairPartial[(size_t)t * 2 + 0];
    float c2 = pairPartial[(size_t)t * 2 + 1];
    __shared__ float rli[4], rs[4], rc[4];
    const float rl = wredsum(d2);
    const float ss2 = wredsum(s);
    const float cc = wredsum(c2);
    const int lane = t & 63, wv = t >> 6;
    if (lane == 0) { rli[wv] = rl; rs[wv] = ss2; rc[wv] = cc; }
    __syncthreads();
    if (t == 0) {
        const float tot = rli[0] + rli[1] + rli[2] + rli[3];
        out[0] = tot / (3.0f * (float)B_) / (float)B_;
        const float S = rs[0] + rs[1] + rs[2] + rs[3];
        const float C = rc[0] + rc[1] + rc[2] + rc[3];
        out[1] = (C > 0.f) ? (S / C) : 0.f;
    }
}

// ---------------------------------------------------------------------------
extern "C" void kernel_launch(void* const* d_in, const int* in_sizes, int n_in,
                              void* d_out, int out_size, void* d_ws, size_t ws_size,
                              hipStream_t stream) {
    const float* smpl = (const float*)d_in[0];
    const float* obj  = (const float*)d_in[1];
    const float* Ks   = (const float*)d_in[2];
    const int*   sidx = (const int*)d_in[3];
    const int*   oidx = (const int*)d_in[4];
    float* out = (float*)d_out;

    float* w = (float*)d_ws;
    float* sumO   = w;                                     // 256*16*3 = 12288
    float* sumS   = sumO + (size_t)B_ * NBLK_O * 3;        // 256*4*3  = 3072
    float* splitS = sumS + (size_t)B_ * NBLK_S * 3;        // 256*8*2*9 = 36864
    float* splitO = splitS + (size_t)B_ * P_ * DIVS_ * 9;  // 256*8*4*9 = 73728
    float* pairP  = splitO + (size_t)B_ * P_ * DIVO_ * 9;  // 512

    phase1_kernel<<<B_ * UNITS_PER_B, 256, 0, stream>>>(
        obj, smpl, Ks, sidx, oidx, sumO, sumS, splitO, splitS);
    pair_kernel<<<B_, 64, 0, stream>>>(splitS, splitO, pairP);
    last_kernel<<<1, 256, 0, stream>>>(sumS, sumO, pairP, out);
}